// Round 4
// baseline (505.061 us; speedup 1.0000x reference)
//
#include <hip/hip_runtime.h>
#include <hip/hip_bf16.h>
#include <hip/hip_fp8.h>

// x: (64,3,384,384) f32; conv_w: (768,3,16,16) f32; conv_b: (768,) f32; latent: (1,1024,768) f32
// patches 24x24=576/img, M=36864, K=768, L=1024. pn padded to 640 rows/batch (5x128 tiles).
// All GEMMs in OCP fp8 e4m3 via MX-scaled MFMA 16x16x128 (K-tile 128, 6 iters).
// Scale encoding (e8m0): 127 -> 2^0, 123 -> 2^-4, 122 -> 2^-5.
//
// REGISTER ALLOCATION NOTES:
//  * 32x32x64 MFMA path: acc alone = 256 regs -> unfittable, 450-553 MB spill
//    under any bounds (R5-R8). Keep 16x16x128.
//  * R11 post-mortem: VGPR_Count 196 arch + 64 AGPR acc = 260/wave on the unified
//    file -> 1 wave/SIMD (512-reg file) -> ONE block per CU -> all pipeline phases
//    (ds_read ~770cy, MFMA ~550cy, vmcnt latency, 2 barriers) strictly serial.
//    That is why MfmaUtil was pinned at ~15% through R9-R11 regardless of
//    schedule. 4 registers over the cliff.
//  * R12 (this round): __launch_bounds__(256, 2) on the GEMM kernels only
//    (2 waves/EU = 2 blocks/CU). Allocator must shave 4 arch regs (196->192);
//    the al/ah->a repack slack (~64 regs held live) gives it plenty of room.
//    This is NOT the R5-R8 pathology: there the floor was unfittable.
#define KDIM   768
#define NPATCH 576
#define NPAD   640
#define NBATCH 64
#define MROWS  36864
#define LROWS  1024

typedef __attribute__((ext_vector_type(8))) int int8v;
typedef __attribute__((ext_vector_type(4))) int int4v;
typedef __attribute__((ext_vector_type(4))) float float4v;
typedef unsigned char u8;

__device__ inline u8 f2fp8(float f) { __hip_fp8_e4m3 t(f); return (u8)t.__x; }

__device__ __forceinline__ void gload_lds16(const u8* g, u8* l) {
    __builtin_amdgcn_global_load_lds(
        (const __attribute__((address_space(1))) unsigned int*)g,
        (__attribute__((address_space(3))) unsigned int*)l, 16, 0, 0);
}

// 32B LDS fragment read as two ds_read_b128, invisible to the waitcnt legalizer.
// addr = 32-bit LDS byte offset (low 32 bits of a generic LDS pointer on gfx9+).
__device__ __forceinline__ void ds_read_b256(unsigned addr, int4v& lo, int4v& hi) {
    asm volatile("ds_read_b128 %0, %2\n\tds_read_b128 %1, %2 offset:16"
                 : "=&v"(lo), "=&v"(hi) : "v"(addr));
}

// ---------------- im2col + fp8 cast (scale 1), 16 contiguous floats per thread ------
__global__ __launch_bounds__(256) void im2col_cast_v(const float* __restrict__ x,
                                                     u8* __restrict__ A) {
    int t = blockIdx.x * 256 + threadIdx.x;        // 36864*48 threads
    int row = t / 48;
    int ci = t - row * 48;                         // c*16 + i
    int c = ci >> 4, i = ci & 15;
    int b = row / NPATCH;
    int p = row - b * NPATCH;
    int ph = p / 24, pw = p - ph * 24;
    const float* src = x + (((size_t)b * 3 + c) * 384 + ph * 16 + i) * 384 + pw * 16;
    float4v f[4];
#pragma unroll
    for (int q = 0; q < 4; q++) f[q] = *(const float4v*)(src + q * 4);
    unsigned int o[4];
#pragma unroll
    for (int q = 0; q < 4; q++) {
        o[q] = 0;
#pragma unroll
        for (int e = 0; e < 4; e++) o[q] |= ((unsigned int)f2fp8(f[q][e])) << (8 * e);
    }
    *(int4v*)(A + (size_t)row * KDIM + c * 256 + i * 16) = *(int4v*)o;
}

// ---------------- conv_w -> fp8(w*32), used with B-scale 2^-5 ------------------------
__global__ __launch_bounds__(256) void cast_w(const float* __restrict__ src,
                                              u8* __restrict__ dst) {
    int t = blockIdx.x * 256 + threadIdx.x;        // 36864 threads, 16 elems each
    const float* s = src + (size_t)t * 16;
    unsigned int o[4];
#pragma unroll
    for (int q = 0; q < 4; q++) {
        float4v f = *(const float4v*)(s + q * 4);
        o[q] = 0;
#pragma unroll
        for (int e = 0; e < 4; e++) o[q] |= ((unsigned int)f2fp8(f[e] * 32.0f)) << (8 * e);
    }
    *(int4v*)(dst + (size_t)t * 16) = *(int4v*)o;
}

// ---------------- latent: L2-normalize f32 -> fp8(ln*16), one wave per row -----------
__global__ __launch_bounds__(256) void normalize_latent(const float* __restrict__ src,
                                                        u8* __restrict__ dst) {
    int wave = threadIdx.x >> 6, lane = threadIdx.x & 63;
    int row = blockIdx.x * 4 + wave;               // 256 blocks
    const float4v* pr = (const float4v*)(src + (size_t)row * KDIM);
    float4v v[3];
    float ss = 0.f;
#pragma unroll
    for (int c = 0; c < 3; c++) {
        v[c] = pr[lane + 64 * c];
#pragma unroll
        for (int e = 0; e < 4; e++) ss += v[c][e] * v[c][e];
    }
#pragma unroll
    for (int off = 32; off; off >>= 1) ss += __shfl_xor(ss, off);
    float scale = 16.0f / fmaxf(sqrtf(ss), 1e-8f);
#pragma unroll
    for (int c = 0; c < 3; c++) {
        unsigned int o = 0;
#pragma unroll
        for (int e = 0; e < 4; e++) o |= ((unsigned int)f2fp8(v[c][e] * scale)) << (8 * e);
        *(unsigned int*)(dst + (size_t)row * KDIM + c * 256 + lane * 4) = o;
    }
}

// ---------------- inverse row norms from summed squares (padded index space) --------
__global__ __launch_bounds__(256) void inv_norm(const float* __restrict__ rssq,
                                                float* __restrict__ rn) {
    int t = blockIdx.x * 256 + threadIdx.x;        // 160 blocks -> 40960
    int p = t % NPAD;
    rn[t] = (p < NPATCH) ? (1.0f / fmaxf(sqrtf(rssq[t]), 1e-8f)) : 0.0f;
}

// ---------------- fp8 MX GEMM mainloop (C = A . B^T, both row-major K, fp8) ----------
// 256 threads, 4 waves 2x2, each wave 64x64 = 4x4 frags of 16x16x128 scaled MFMA.
// Double-buffered LDS tiles 2x 128x128 fp8 per operand, global_load_lds width 16.
// 32B-granule XOR swizzle on both stage-source and read.
// T3/T4 pipeline with EARLY buffer-free barrier:
//   issue prefetch(t+1) ; vmcnt(8) ; barrier ; ds_read(cur) ; lgkmcnt(0) ;
//   barrier ; MFMA (no trailing barrier -> overlaps next iter's stage phase)
__device__ __forceinline__ void gemm_mainloop_fp8(const u8* __restrict__ Ab,
                                                  const u8* __restrict__ Bb,
                                                  u8* As, u8* Bs,
                                                  float4v acc[4][4], int sA, int sB) {
    int tid = threadIdx.x;
    int lane = tid & 63;
    int wu = __builtin_amdgcn_readfirstlane(tid >> 6);   // wave id in SGPR
    int quad = lane >> 4, l15 = lane & 15;
    int wm = wu & 1, wn = wu >> 1;
    int lr = lane >> 3, ls = lane & 7;             // staging: 8 lanes x 16B per row
    int gs = ((((ls >> 1) - lr) & 3) << 1) | (ls & 1);   // swizzled global 16B seg
    int gvoff = lr * KDIM + gs * 16;               // per-lane byte offset (1 VGPR)
    const u8* gAu = Ab + (size_t)(wu * 32) * KDIM; // uniform bases (SGPR pairs)
    const u8* gBu = Bb + (size_t)(wu * 32) * KDIM;
    int woffL = wu * 32 * 128;                     // wave-uniform LDS offset
    int lg = ((quad + (l15 & 3)) & 3) * 32;        // swizzled 32B granule for reads
    unsigned asb = (unsigned)(size_t)As + (unsigned)((wm * 64 + l15) * 128 + lg);
    unsigned bsb = (unsigned)(size_t)Bs + (unsigned)((wn * 64 + l15) * 128 + lg);

    // prologue: stage tile 0 into buffer 0
#pragma unroll
    for (int i = 0; i < 4; i++) {
        gload_lds16(gAu + i * 8 * KDIM + gvoff, As + woffL + i * 1024);
        gload_lds16(gBu + i * 8 * KDIM + gvoff, Bs + woffL + i * 1024);
    }
#pragma unroll
    for (int t = 0; t < 6; t++) {
        int cur = (t & 1) * 16384;
        if (t < 5) {
            // prefetch tile t+1 into the other buffer. Safe: that buffer's reads
            // completed at iter t-1's post-read barrier (we are past it).
            int nxt = ((t + 1) & 1) * 16384;
            int ks = (t + 1) * 128;
#pragma unroll
            for (int i = 0; i < 4; i++) {
                gload_lds16(gAu + ks + i * 8 * KDIM + gvoff, As + nxt + woffL + i * 1024);
                gload_lds16(gBu + ks + i * 8 * KDIM + gvoff, Bs + nxt + woffL + i * 1024);
            }
            asm volatile("s_waitcnt vmcnt(8)" ::: "memory");  // tile t landed; t+1 in flight
        } else {
            asm volatile("s_waitcnt vmcnt(0)" ::: "memory");  // last tile: drain
        }
        __builtin_amdgcn_s_barrier();              // #1: tile t visible to all waves
        asm volatile("" ::: "memory");
        int4v al[4], ah[4], bl[4], bh[4];
#pragma unroll
        for (int j = 0; j < 4; j++) ds_read_b256(bsb + cur + j * 2048, bl[j], bh[j]);
#pragma unroll
        for (int i = 0; i < 4; i++) ds_read_b256(asb + cur + i * 2048, al[i], ah[i]);
        // single LDS wait; all 16 dest tuples tied so every consumer data-depends
        asm volatile("s_waitcnt lgkmcnt(0)"
                     : "+v"(al[0]), "+v"(al[1]), "+v"(al[2]), "+v"(al[3]),
                       "+v"(ah[0]), "+v"(ah[1]), "+v"(ah[2]), "+v"(ah[3]),
                       "+v"(bl[0]), "+v"(bl[1]), "+v"(bl[2]), "+v"(bl[3]),
                       "+v"(bh[0]), "+v"(bh[1]), "+v"(bh[2]), "+v"(bh[3]));
        __builtin_amdgcn_sched_barrier(0);
        __builtin_amdgcn_s_barrier();              // #2 (EARLY): all reads in regs ->
        asm volatile("" ::: "memory");             // buffer free for next prefetch
        int8v a[4], b[4];
#pragma unroll
        for (int i = 0; i < 4; i++)
            a[i] = __builtin_shufflevector(al[i], ah[i], 0, 1, 2, 3, 4, 5, 6, 7);
#pragma unroll
        for (int j = 0; j < 4; j++)
            b[j] = __builtin_shufflevector(bl[j], bh[j], 0, 1, 2, 3, 4, 5, 6, 7);
        __builtin_amdgcn_s_setprio(1);
#pragma unroll
        for (int i = 0; i < 4; i++)
#pragma unroll
            for (int j = 0; j < 4; j++)
                acc[i][j] = __builtin_amdgcn_mfma_scale_f32_16x16x128_f8f6f4(
                    a[i], b[j], acc[i][j], 0, 0, 0, sA, 0, sB);
        __builtin_amdgcn_s_setprio(0);
        // no trailing barrier: MFMA overlaps next iteration's stage/wait/read phases
    }
}

__device__ __forceinline__ float block_reduce_sum(float s, float* red) {
#pragma unroll
    for (int off = 32; off; off >>= 1) s += __shfl_down(s, off);
    int wave = threadIdx.x >> 6, lane = threadIdx.x & 63;
    if (lane == 0) red[wave] = s;
    __syncthreads();
    return red[0] + red[1] + red[2] + red[3];
}

// ---------------- conv GEMM: A(x,s=1) . Wm^T(w*32,s=2^-5) + bias -> pn fp8(v*16) -----
__global__ __launch_bounds__(256, 2) void gemm_conv(const u8* __restrict__ A,
                                                    const u8* __restrict__ Wm,
                                                    const float* __restrict__ bias,
                                                    u8* __restrict__ pn,
                                                    float* __restrict__ rssq) {
    __shared__ u8 As[2 * 128 * 128], Bs[2 * 128 * 128];
    int xcd = blockIdx.x & 7, q = blockIdx.x >> 3;   // 1728 blocks: 288 mb x 6 nb
    int mb = xcd * 36 + q / 6;                       // contiguous mb strip per XCD
    int nb = q % 6;
    int wave = threadIdx.x >> 6, lane = threadIdx.x & 63;
    int quad = lane >> 4, l15 = lane & 15;
    int wm = wave & 1, wn = wave >> 1;
    float4v acc[4][4] = {};
    gemm_mainloop_fp8(A + (size_t)mb * 128 * KDIM, Wm + (size_t)nb * 128 * KDIM,
                      As, Bs, acc, 0x7F7F7F7F, 0x7A7A7A7A);
    float bv[4];
#pragma unroll
    for (int j = 0; j < 4; j++) bv[j] = bias[nb * 128 + wn * 64 + j * 16 + l15];
#pragma unroll
    for (int i = 0; i < 4; i++) {
#pragma unroll
        for (int r = 0; r < 4; r++) {
            int row = mb * 128 + wm * 64 + i * 16 + quad * 4 + r;
            int b = row / NPATCH;
            int prow = row + b * 64;               // padded row index
            float ssq = 0.f;
#pragma unroll
            for (int j = 0; j < 4; j++) {
                int col = nb * 128 + wn * 64 + j * 16 + l15;
                float v = acc[i][j][r] + bv[j];
                ssq += v * v;
                pn[(size_t)prow * KDIM + col] = f2fp8(v * 16.0f);
            }
#pragma unroll
            for (int off = 1; off < 16; off <<= 1) ssq += __shfl_xor(ssq, off);
            if (l15 == 0) atomicAdd(&rssq[prow], ssq);
        }
    }
}

// ---------------- merged scores kernel --------------------------------------------
// blocks [0, 2560):   close GEMM  pn . Lm^T, per-batch close_sum
// blocks [2560, 3520): sim GEMM   pn . pn^T, symmetric: 5 diag + 10 upper tiles
//                      per batch, off-diag tile sums doubled. far_sum.
__global__ __launch_bounds__(256, 2) void gemm_scores(const u8* __restrict__ pn,
                                                      const u8* __restrict__ Lm,
                                                      const float* __restrict__ rn,
                                                      float* __restrict__ far_sum,
                                                      float* __restrict__ close_sum) {
    __shared__ u8 As[2 * 128 * 128], Bs[2 * 128 * 128];
    __shared__ float red[4];
    int wave = threadIdx.x >> 6, lane = threadIdx.x & 63;
    int quad = lane >> 4, l15 = lane & 15;
    int wm = wave & 1, wn = wave >> 1;
    float4v acc[4][4] = {};

    if (blockIdx.x < 2560) {
        // ---- close path: 2560 blocks = 320 mb x 8 nb
        int xcd = blockIdx.x & 7, q = blockIdx.x >> 3;
        int mb = xcd * 40 + (q >> 3);                // contiguous mb strip per XCD
        int nb = q & 7;
        gemm_mainloop_fp8(pn + (size_t)mb * 128 * KDIM, Lm + (size_t)nb * 128 * KDIM,
                          As, Bs, acc, 0x7B7B7B7B, 0x7B7B7B7B);
        int batch = mb / 5;
        int ptile = (mb - batch * 5) * 128;          // row offset within batch
        float s = 0.f;
#pragma unroll
        for (int i = 0; i < 4; i++) {
#pragma unroll
            for (int r = 0; r < 4; r++) {
                int p = ptile + wm * 64 + i * 16 + quad * 4 + r;
                if (p < NPATCH) {
                    float rrow = rn[batch * NPAD + p];
#pragma unroll
                    for (int j = 0; j < 4; j++) s += __expf(2.0f * acc[i][j][r] * rrow);
                }
            }
        }
        float tot = block_reduce_sum(s, red);
        if (threadIdx.x == 0) atomicAdd(&close_sum[batch], tot);
    } else {
        // ---- sim path: 960 blocks = 64 batches x 15 tiles (5 diag + 10 upper)
        int sbid = blockIdx.x - 2560;
        int xcd = sbid & 7, q = sbid >> 3;           // q in [0,120)
        int b = xcd * 8 + q / 15;
        int t = q % 15;
        int mt, nt;
        if (t < 5) { mt = t; nt = t; }
        else {
            int u = t - 5;                           // upper-triangle pair index
            mt = (u < 4) ? 0 : (u < 7) ? 1 : (u < 9) ? 2 : 3;
            nt = (u < 4) ? u + 1 : (u < 7) ? u - 2 : (u < 9) ? u - 5 : 4;
        }
        const u8* base = pn + (size_t)b * NPAD * KDIM;
        gemm_mainloop_fp8(base + (size_t)mt * 128 * KDIM, base + (size_t)nt * 128 * KDIM,
                          As, Bs, acc, 0x7B7B7B7B, 0x7B7B7B7B);
        const float* rnb = rn + b * NPAD;
        float rcol[4];
#pragma unroll
        for (int j = 0; j < 4; j++) rcol[j] = rnb[nt * 128 + wn * 64 + j * 16 + l15];
        float s = 0.f;
#pragma unroll
        for (int i = 0; i < 4; i++) {
#pragma unroll
            for (int r = 0; r < 4; r++) {
                int row = mt * 128 + wm * 64 + i * 16 + quad * 4 + r;
                if (row < NPATCH) {
                    float rrow = rnb[row];
#pragma unroll
                    for (int j = 0; j < 4; j++) {
                        int col = nt * 128 + wn * 64 + j * 16 + l15;
                        if (col < NPATCH && row != col)
                            s += __expf(2.0f * acc[i][j][r] * rrow * rcol[j]);
                    }
                }
            }
        }
        if (mt != nt) s *= 2.0f;                     // mirror tile contributes equally
        float tot = block_reduce_sum(s, red);
        if (threadIdx.x == 0) atomicAdd(&far_sum[b], tot);
    }
}

// ---------------- final loss ----------------
__global__ void loss_kernel(const float* __restrict__ far_sum,
                            const float* __restrict__ close_sum,
                            float* __restrict__ out) {
    int t = threadIdx.x;  // 64
    float v = logf(far_sum[t]) - logf(close_sum[t]);
#pragma unroll
    for (int off = 32; off; off >>= 1) v += __shfl_xor(v, off);
    if (t == 0) out[0] = v * (1.0f / 64.0f);
}

extern "C" void kernel_launch(void* const* d_in, const int* in_sizes, int n_in,
                              void* d_out, int out_size, void* d_ws, size_t ws_size,
                              hipStream_t stream) {
    const float* x      = (const float*)d_in[0];
    const float* conv_w = (const float*)d_in[1];
    const float* conv_b = (const float*)d_in[2];
    const float* latent = (const float*)d_in[3];
    float* out = (float*)d_out;
    char* ws = (char*)d_ws;

    // workspace layout (bytes):
    // pn (40960x768 fp8, 640 rows/batch):  0          .. 31,457,280
    // A  (im2col 36864x768 fp8):           31,457,280 .. 59,768,832
    //   rn (40960 f32) overlays A (A dead after gemm_conv; rn written after)
    // Wm (768x768 fp8, *32):               59,768,832 .. 60,358,656
    // Lm (1024x768 fp8, *16):              60,358,656 .. 61,145,088
    // rssq (40960 f32) + sums (128 f32):   61,145,088 .. 61,309,440
    u8* pn = (u8*)ws;
    u8* A  = (u8*)(ws + 31457280);
    u8* Wm = (u8*)(ws + 59768832);
    u8* Lm = (u8*)(ws + 60358656);
    float* rssq = (float*)(ws + 61145088);
    float* sums = (float*)(ws + 61308928);
    float* rn   = (float*)(ws + 31457280);   // overlays A
    float* far_sum = sums;
    float* close_sum = sums + 64;

    hipMemsetAsync(rssq, 0, (40960 + 128) * sizeof(float), stream);  // rssq + sums
    im2col_cast_v<<<36864 * 48 / 256, 256, 0, stream>>>(x, A);
    cast_w<<<144, 256, 0, stream>>>(conv_w, Wm);
    normalize_latent<<<LROWS / 4, 256, 0, stream>>>(latent, Lm);

    gemm_conv<<<288 * 6, 256, 0, stream>>>(A, Wm, conv_b, pn, rssq);
    inv_norm<<<160, 256, 0, stream>>>(rssq, rn);

    gemm_scores<<<2560 + 960, 256, 0, stream>>>(pn, Lm, rn, far_sum, close_sum);

    loss_kernel<<<1, 64, 0, stream>>>(far_sum, close_sum, out);
}

// Round 5
// 291.429 us; speedup vs baseline: 1.7330x; 1.7330x over previous
//
#include <hip/hip_runtime.h>
#include <hip/hip_bf16.h>
#include <hip/hip_fp8.h>

// x: (64,3,384,384) f32; conv_w: (768,3,16,16) f32; conv_b: (768,) f32; latent: (1,1024,768) f32
// patches 24x24=576/img, M=36864, K=768, L=1024. pn padded to 640 rows/batch (5x128 tiles).
// All GEMMs in OCP fp8 e4m3 via MX-scaled MFMA 16x16x128 (K-tile 128, 6 iters).
// Scale encoding (e8m0): 127 -> 2^0, 123 -> 2^-4, 122 -> 2^-5.
//
// REGISTER MODEL (confirmed R11+R12):
//  * unified RF: 512 regs/SIMD budget at 2 waves -> need arch+acc <= 256/wave.
//  * R11: 196 arch + 64 acc = 260 -> 1 wave/SIMD, 10.4% occ, MfmaUtil ~15%.
//  * R12: __launch_bounds__(256,2) forced it -> 128 arch (68 spilled!), 327 MB
//    scratch writes, 2x slower. NEVER force bounds here; shave regs manually.
//  * R13 (this round): revert bounds; cap live ranges instead:
//     - K-loop rolled (#pragma unroll 1) so the scheduler cannot extend
//       prefetch/copy live ranges across the 6 unrolled iterations;
//     - split lgkmcnt wait (8 -> B tuples, then 0 -> A tuples; DS returns are
//       in-order) so B intermediates retire while A reads are in flight.
//    Target: arch <= 192 (total 256) WITHOUT spill (WRITE_SIZE must stay ~110KB).
#define KDIM   768
#define NPATCH 576
#define NPAD   640
#define NBATCH 64
#define MROWS  36864
#define LROWS  1024

typedef __attribute__((ext_vector_type(8))) int int8v;
typedef __attribute__((ext_vector_type(4))) int int4v;
typedef __attribute__((ext_vector_type(4))) float float4v;
typedef unsigned char u8;

__device__ inline u8 f2fp8(float f) { __hip_fp8_e4m3 t(f); return (u8)t.__x; }

__device__ __forceinline__ void gload_lds16(const u8* g, u8* l) {
    __builtin_amdgcn_global_load_lds(
        (const __attribute__((address_space(1))) unsigned int*)g,
        (__attribute__((address_space(3))) unsigned int*)l, 16, 0, 0);
}

// 32B LDS fragment read as two ds_read_b128, invisible to the waitcnt legalizer.
// addr = 32-bit LDS byte offset (low 32 bits of a generic LDS pointer on gfx9+).
__device__ __forceinline__ void ds_read_b256(unsigned addr, int4v& lo, int4v& hi) {
    asm volatile("ds_read_b128 %0, %2\n\tds_read_b128 %1, %2 offset:16"
                 : "=&v"(lo), "=&v"(hi) : "v"(addr));
}

// ---------------- im2col + fp8 cast (scale 1), 16 contiguous floats per thread ------
__global__ __launch_bounds__(256) void im2col_cast_v(const float* __restrict__ x,
                                                     u8* __restrict__ A) {
    int t = blockIdx.x * 256 + threadIdx.x;        // 36864*48 threads
    int row = t / 48;
    int ci = t - row * 48;                         // c*16 + i
    int c = ci >> 4, i = ci & 15;
    int b = row / NPATCH;
    int p = row - b * NPATCH;
    int ph = p / 24, pw = p - ph * 24;
    const float* src = x + (((size_t)b * 3 + c) * 384 + ph * 16 + i) * 384 + pw * 16;
    float4v f[4];
#pragma unroll
    for (int q = 0; q < 4; q++) f[q] = *(const float4v*)(src + q * 4);
    unsigned int o[4];
#pragma unroll
    for (int q = 0; q < 4; q++) {
        o[q] = 0;
#pragma unroll
        for (int e = 0; e < 4; e++) o[q] |= ((unsigned int)f2fp8(f[q][e])) << (8 * e);
    }
    *(int4v*)(A + (size_t)row * KDIM + c * 256 + i * 16) = *(int4v*)o;
}

// ---------------- conv_w -> fp8(w*32), used with B-scale 2^-5 ------------------------
__global__ __launch_bounds__(256) void cast_w(const float* __restrict__ src,
                                              u8* __restrict__ dst) {
    int t = blockIdx.x * 256 + threadIdx.x;        // 36864 threads, 16 elems each
    const float* s = src + (size_t)t * 16;
    unsigned int o[4];
#pragma unroll
    for (int q = 0; q < 4; q++) {
        float4v f = *(const float4v*)(s + q * 4);
        o[q] = 0;
#pragma unroll
        for (int e = 0; e < 4; e++) o[q] |= ((unsigned int)f2fp8(f[e] * 32.0f)) << (8 * e);
    }
    *(int4v*)(dst + (size_t)t * 16) = *(int4v*)o;
}

// ---------------- latent: L2-normalize f32 -> fp8(ln*16), one wave per row -----------
__global__ __launch_bounds__(256) void normalize_latent(const float* __restrict__ src,
                                                        u8* __restrict__ dst) {
    int wave = threadIdx.x >> 6, lane = threadIdx.x & 63;
    int row = blockIdx.x * 4 + wave;               // 256 blocks
    const float4v* pr = (const float4v*)(src + (size_t)row * KDIM);
    float4v v[3];
    float ss = 0.f;
#pragma unroll
    for (int c = 0; c < 3; c++) {
        v[c] = pr[lane + 64 * c];
#pragma unroll
        for (int e = 0; e < 4; e++) ss += v[c][e] * v[c][e];
    }
#pragma unroll
    for (int off = 32; off; off >>= 1) ss += __shfl_xor(ss, off);
    float scale = 16.0f / fmaxf(sqrtf(ss), 1e-8f);
#pragma unroll
    for (int c = 0; c < 3; c++) {
        unsigned int o = 0;
#pragma unroll
        for (int e = 0; e < 4; e++) o |= ((unsigned int)f2fp8(v[c][e] * scale)) << (8 * e);
        *(unsigned int*)(dst + (size_t)row * KDIM + c * 256 + lane * 4) = o;
    }
}

// ---------------- inverse row norms from summed squares (padded index space) --------
__global__ __launch_bounds__(256) void inv_norm(const float* __restrict__ rssq,
                                                float* __restrict__ rn) {
    int t = blockIdx.x * 256 + threadIdx.x;        // 160 blocks -> 40960
    int p = t % NPAD;
    rn[t] = (p < NPATCH) ? (1.0f / fmaxf(sqrtf(rssq[t]), 1e-8f)) : 0.0f;
}

// ---------------- fp8 MX GEMM mainloop (C = A . B^T, both row-major K, fp8) ----------
// 256 threads, 4 waves 2x2, each wave 64x64 = 4x4 frags of 16x16x128 scaled MFMA.
// Double-buffered LDS tiles 2x 128x128 fp8 per operand, global_load_lds width 16.
// 32B-granule XOR swizzle on both stage-source and read.
// T3/T4 pipeline, EARLY buffer-free barrier, ROLLED K-loop (register pressure):
//   issue prefetch(t+1) ; vmcnt(8) ; barrier ; ds_read(cur) ; lgkm(8)+pack B ;
//   lgkm(0)+pack A ; barrier ; MFMA  (no trailing barrier)
__device__ __forceinline__ void gemm_mainloop_fp8(const u8* __restrict__ Ab,
                                                  const u8* __restrict__ Bb,
                                                  u8* As, u8* Bs,
                                                  float4v acc[4][4], int sA, int sB) {
    int tid = threadIdx.x;
    int lane = tid & 63;
    int wu = __builtin_amdgcn_readfirstlane(tid >> 6);   // wave id in SGPR
    int quad = lane >> 4, l15 = lane & 15;
    int wm = wu & 1, wn = wu >> 1;
    int lr = lane >> 3, ls = lane & 7;             // staging: 8 lanes x 16B per row
    int gs = ((((ls >> 1) - lr) & 3) << 1) | (ls & 1);   // swizzled global 16B seg
    int gvoff = lr * KDIM + gs * 16;               // per-lane byte offset (1 VGPR)
    const u8* gAu = Ab + (size_t)(wu * 32) * KDIM; // uniform bases (SGPR pairs)
    const u8* gBu = Bb + (size_t)(wu * 32) * KDIM;
    int woffL = wu * 32 * 128;                     // wave-uniform LDS offset
    int lg = ((quad + (l15 & 3)) & 3) * 32;        // swizzled 32B granule for reads
    unsigned asb = (unsigned)(size_t)As + (unsigned)((wm * 64 + l15) * 128 + lg);
    unsigned bsb = (unsigned)(size_t)Bs + (unsigned)((wn * 64 + l15) * 128 + lg);

    // prologue: stage tile 0 into buffer 0
#pragma unroll
    for (int i = 0; i < 4; i++) {
        gload_lds16(gAu + i * 8 * KDIM + gvoff, As + woffL + i * 1024);
        gload_lds16(gBu + i * 8 * KDIM + gvoff, Bs + woffL + i * 1024);
    }
    // ROLLED loop: full unroll let the scheduler stretch live ranges across all
    // 6 iterations -> 196 arch VGPR -> 1 wave/SIMD (R11). Rolling caps pressure.
#pragma unroll 1
    for (int t = 0; t < 6; t++) {
        int cur = (t & 1) * 16384;
        if (t < 5) {
            // prefetch tile t+1 into the other buffer. Safe: that buffer's reads
            // completed at iter t-1's post-read barrier (we are past it).
            int nxt = ((t + 1) & 1) * 16384;
            int ks = (t + 1) * 128;
#pragma unroll
            for (int i = 0; i < 4; i++) {
                gload_lds16(gAu + ks + i * 8 * KDIM + gvoff, As + nxt + woffL + i * 1024);
                gload_lds16(gBu + ks + i * 8 * KDIM + gvoff, Bs + nxt + woffL + i * 1024);
            }
            asm volatile("s_waitcnt vmcnt(8)" ::: "memory");  // tile t landed; t+1 in flight
        } else {
            asm volatile("s_waitcnt vmcnt(0)" ::: "memory");  // last tile: drain
        }
        __builtin_amdgcn_s_barrier();              // #1: tile t visible to all waves
        asm volatile("" ::: "memory");
        int4v al[4], ah[4], bl[4], bh[4];
#pragma unroll
        for (int j = 0; j < 4; j++) ds_read_b256(bsb + cur + j * 2048, bl[j], bh[j]);
#pragma unroll
        for (int i = 0; i < 4; i++) ds_read_b256(asb + cur + i * 2048, al[i], ah[i]);
        // DS returns are in-order: lgkmcnt(8) = the 8 B-reads are done.
        asm volatile("s_waitcnt lgkmcnt(8)"
                     : "+v"(bl[0]), "+v"(bl[1]), "+v"(bl[2]), "+v"(bl[3]),
                       "+v"(bh[0]), "+v"(bh[1]), "+v"(bh[2]), "+v"(bh[3]));
        int8v b[4];
#pragma unroll
        for (int j = 0; j < 4; j++)
            b[j] = __builtin_shufflevector(bl[j], bh[j], 0, 1, 2, 3, 4, 5, 6, 7);
        asm volatile("s_waitcnt lgkmcnt(0)"
                     : "+v"(al[0]), "+v"(al[1]), "+v"(al[2]), "+v"(al[3]),
                       "+v"(ah[0]), "+v"(ah[1]), "+v"(ah[2]), "+v"(ah[3]));
        int8v a[4];
#pragma unroll
        for (int i = 0; i < 4; i++)
            a[i] = __builtin_shufflevector(al[i], ah[i], 0, 1, 2, 3, 4, 5, 6, 7);
        __builtin_amdgcn_sched_barrier(0);
        __builtin_amdgcn_s_barrier();              // #2 (EARLY): all reads in regs ->
        asm volatile("" ::: "memory");             // buffer free for next prefetch
        __builtin_amdgcn_s_setprio(1);
#pragma unroll
        for (int i = 0; i < 4; i++)
#pragma unroll
            for (int j = 0; j < 4; j++)
                acc[i][j] = __builtin_amdgcn_mfma_scale_f32_16x16x128_f8f6f4(
                    a[i], b[j], acc[i][j], 0, 0, 0, sA, 0, sB);
        __builtin_amdgcn_s_setprio(0);
        // no trailing barrier: MFMA overlaps next iteration's stage/wait/read phases
    }
}

__device__ __forceinline__ float block_reduce_sum(float s, float* red) {
#pragma unroll
    for (int off = 32; off; off >>= 1) s += __shfl_down(s, off);
    int wave = threadIdx.x >> 6, lane = threadIdx.x & 63;
    if (lane == 0) red[wave] = s;
    __syncthreads();
    return red[0] + red[1] + red[2] + red[3];
}

// ---------------- conv GEMM: A(x,s=1) . Wm^T(w*32,s=2^-5) + bias -> pn fp8(v*16) -----
__global__ __launch_bounds__(256) void gemm_conv(const u8* __restrict__ A,
                                                 const u8* __restrict__ Wm,
                                                 const float* __restrict__ bias,
                                                 u8* __restrict__ pn,
                                                 float* __restrict__ rssq) {
    __shared__ u8 As[2 * 128 * 128], Bs[2 * 128 * 128];
    int xcd = blockIdx.x & 7, q = blockIdx.x >> 3;   // 1728 blocks: 288 mb x 6 nb
    int mb = xcd * 36 + q / 6;                       // contiguous mb strip per XCD
    int nb = q % 6;
    int wave = threadIdx.x >> 6, lane = threadIdx.x & 63;
    int quad = lane >> 4, l15 = lane & 15;
    int wm = wave & 1, wn = wave >> 1;
    float4v acc[4][4] = {};
    gemm_mainloop_fp8(A + (size_t)mb * 128 * KDIM, Wm + (size_t)nb * 128 * KDIM,
                      As, Bs, acc, 0x7F7F7F7F, 0x7A7A7A7A);
    float bv[4];
#pragma unroll
    for (int j = 0; j < 4; j++) bv[j] = bias[nb * 128 + wn * 64 + j * 16 + l15];
#pragma unroll
    for (int i = 0; i < 4; i++) {
#pragma unroll
        for (int r = 0; r < 4; r++) {
            int row = mb * 128 + wm * 64 + i * 16 + quad * 4 + r;
            int b = row / NPATCH;
            int prow = row + b * 64;               // padded row index
            float ssq = 0.f;
#pragma unroll
            for (int j = 0; j < 4; j++) {
                int col = nb * 128 + wn * 64 + j * 16 + l15;
                float v = acc[i][j][r] + bv[j];
                ssq += v * v;
                pn[(size_t)prow * KDIM + col] = f2fp8(v * 16.0f);
            }
#pragma unroll
            for (int off = 1; off < 16; off <<= 1) ssq += __shfl_xor(ssq, off);
            if (l15 == 0) atomicAdd(&rssq[prow], ssq);
        }
    }
}

// ---------------- merged scores kernel --------------------------------------------
// blocks [0, 2560):   close GEMM  pn . Lm^T, per-batch close_sum
// blocks [2560, 3520): sim GEMM   pn . pn^T, symmetric: 5 diag + 10 upper tiles
//                      per batch, off-diag tile sums doubled. far_sum.
__global__ __launch_bounds__(256) void gemm_scores(const u8* __restrict__ pn,
                                                   const u8* __restrict__ Lm,
                                                   const float* __restrict__ rn,
                                                   float* __restrict__ far_sum,
                                                   float* __restrict__ close_sum) {
    __shared__ u8 As[2 * 128 * 128], Bs[2 * 128 * 128];
    __shared__ float red[4];
    int wave = threadIdx.x >> 6, lane = threadIdx.x & 63;
    int quad = lane >> 4, l15 = lane & 15;
    int wm = wave & 1, wn = wave >> 1;
    float4v acc[4][4] = {};

    if (blockIdx.x < 2560) {
        // ---- close path: 2560 blocks = 320 mb x 8 nb
        int xcd = blockIdx.x & 7, q = blockIdx.x >> 3;
        int mb = xcd * 40 + (q >> 3);                // contiguous mb strip per XCD
        int nb = q & 7;
        gemm_mainloop_fp8(pn + (size_t)mb * 128 * KDIM, Lm + (size_t)nb * 128 * KDIM,
                          As, Bs, acc, 0x7B7B7B7B, 0x7B7B7B7B);
        int batch = mb / 5;
        int ptile = (mb - batch * 5) * 128;          // row offset within batch
        float s = 0.f;
#pragma unroll
        for (int i = 0; i < 4; i++) {
#pragma unroll
            for (int r = 0; r < 4; r++) {
                int p = ptile + wm * 64 + i * 16 + quad * 4 + r;
                if (p < NPATCH) {
                    float rrow = rn[batch * NPAD + p];
#pragma unroll
                    for (int j = 0; j < 4; j++) s += __expf(2.0f * acc[i][j][r] * rrow);
                }
            }
        }
        float tot = block_reduce_sum(s, red);
        if (threadIdx.x == 0) atomicAdd(&close_sum[batch], tot);
    } else {
        // ---- sim path: 960 blocks = 64 batches x 15 tiles (5 diag + 10 upper)
        int sbid = blockIdx.x - 2560;
        int xcd = sbid & 7, q = sbid >> 3;           // q in [0,120)
        int b = xcd * 8 + q / 15;
        int t = q % 15;
        int mt, nt;
        if (t < 5) { mt = t; nt = t; }
        else {
            int u = t - 5;                           // upper-triangle pair index
            mt = (u < 4) ? 0 : (u < 7) ? 1 : (u < 9) ? 2 : 3;
            nt = (u < 4) ? u + 1 : (u < 7) ? u - 2 : (u < 9) ? u - 5 : 4;
        }
        const u8* base = pn + (size_t)b * NPAD * KDIM;
        gemm_mainloop_fp8(base + (size_t)mt * 128 * KDIM, base + (size_t)nt * 128 * KDIM,
                          As, Bs, acc, 0x7B7B7B7B, 0x7B7B7B7B);
        const float* rnb = rn + b * NPAD;
        float rcol[4];
#pragma unroll
        for (int j = 0; j < 4; j++) rcol[j] = rnb[nt * 128 + wn * 64 + j * 16 + l15];
        float s = 0.f;
#pragma unroll
        for (int i = 0; i < 4; i++) {
#pragma unroll
            for (int r = 0; r < 4; r++) {
                int row = mt * 128 + wm * 64 + i * 16 + quad * 4 + r;
                if (row < NPATCH) {
                    float rrow = rnb[row];
#pragma unroll
                    for (int j = 0; j < 4; j++) {
                        int col = nt * 128 + wn * 64 + j * 16 + l15;
                        if (col < NPATCH && row != col)
                            s += __expf(2.0f * acc[i][j][r] * rrow * rcol[j]);
                    }
                }
            }
        }
        if (mt != nt) s *= 2.0f;                     // mirror tile contributes equally
        float tot = block_reduce_sum(s, red);
        if (threadIdx.x == 0) atomicAdd(&far_sum[b], tot);
    }
}

// ---------------- final loss ----------------
__global__ void loss_kernel(const float* __restrict__ far_sum,
                            const float* __restrict__ close_sum,
                            float* __restrict__ out) {
    int t = threadIdx.x;  // 64
    float v = logf(far_sum[t]) - logf(close_sum[t]);
#pragma unroll
    for (int off = 32; off; off >>= 1) v += __shfl_xor(v, off);
    if (t == 0) out[0] = v * (1.0f / 64.0f);
}

extern "C" void kernel_launch(void* const* d_in, const int* in_sizes, int n_in,
                              void* d_out, int out_size, void* d_ws, size_t ws_size,
                              hipStream_t stream) {
    const float* x      = (const float*)d_in[0];
    const float* conv_w = (const float*)d_in[1];
    const float* conv_b = (const float*)d_in[2];
    const float* latent = (const float*)d_in[3];
    float* out = (float*)d_out;
    char* ws = (char*)d_ws;

    // workspace layout (bytes):
    // pn (40960x768 fp8, 640 rows/batch):  0          .. 31,457,280
    // A  (im2col 36864x768 fp8):           31,457,280 .. 59,768,832
    //   rn (40960 f32) overlays A (A dead after gemm_conv; rn written after)
    // Wm (768x768 fp8, *32):               59,768,832 .. 60,358,656
    // Lm (1024x768 fp8, *16):              60,358,656 .. 61,145,088
    // rssq (40960 f32) + sums (128 f32):   61,145,088 .. 61,309,440
    u8* pn = (u8*)ws;
    u8* A  = (u8*)(ws + 31457280);
    u8* Wm = (u8*)(ws + 59768832);
    u8* Lm = (u8*)(ws + 60358656);
    float* rssq = (float*)(ws + 61145088);
    float* sums = (float*)(ws + 61308928);
    float* rn   = (float*)(ws + 31457280);   // overlays A
    float* far_sum = sums;
    float* close_sum = sums + 64;

    hipMemsetAsync(rssq, 0, (40960 + 128) * sizeof(float), stream);  // rssq + sums
    im2col_cast_v<<<36864 * 48 / 256, 256, 0, stream>>>(x, A);
    cast_w<<<144, 256, 0, stream>>>(conv_w, Wm);
    normalize_latent<<<LROWS / 4, 256, 0, stream>>>(latent, Lm);

    gemm_conv<<<288 * 6, 256, 0, stream>>>(A, Wm, conv_b, pn, rssq);
    inv_norm<<<160, 256, 0, stream>>>(rssq, rn);

    gemm_scores<<<2560 + 960, 256, 0, stream>>>(pn, Lm, rn, far_sum, close_sum);

    loss_kernel<<<1, 64, 0, stream>>>(far_sum, close_sum, out);
}